// Round 1
// baseline (297.622 us; speedup 1.0000x reference)
//
#include <hip/hip_runtime.h>
#include <stdint.h>

#define H 1024
#define LSEQ 4096
#define NBATCH 4
#define MT (NBATCH*LSEQ)   // 16384 rows total

typedef __attribute__((ext_vector_type(8))) short bf16x8;
typedef __attribute__((ext_vector_type(4))) short s16x4;
typedef __attribute__((ext_vector_type(4))) float f32x4;

static __device__ __forceinline__ unsigned short f2bf(float f){
  union { float f; unsigned u; } v; v.f = f;
  unsigned u = v.u;
  return (unsigned short)((u + 0x7FFFu + ((u >> 16) & 1u)) >> 16);  // RNE
}
static __device__ __forceinline__ float bf2f(unsigned short h){
  union { unsigned u; float f; } v; v.u = ((unsigned)h) << 16;
  return v.f;
}
static __device__ __forceinline__ void g2l16(const void* g, void* l){
  __builtin_amdgcn_global_load_lds((const __attribute__((address_space(1))) void*)g,
                                   (__attribute__((address_space(3))) void*)l, 16, 0, 0);
}
static __device__ __forceinline__ f32x4 mfma16(bf16x8 a, bf16x8 b, f32x4 c){
  return __builtin_amdgcn_mfma_f32_16x16x32_bf16(a, b, c, 0, 0, 0);
}

// ---------------- weight prep: Wb = bf16(pw*dw), bias' = pb + db@pw.T ----------
__global__ __launch_bounds__(256) void prep_w(const float* __restrict__ pw,
    const float* __restrict__ dw, const float* __restrict__ db,
    const float* __restrict__ pb, short* __restrict__ wb, float* __restrict__ bo){
  __shared__ float red[256];
  int j = blockIdx.x, t = threadIdx.x;
  const float* row = pw + (size_t)j * H;
  float acc = 0.f;
  #pragma unroll
  for (int k = 0; k < 4; ++k){
    int i = k*256 + t;
    float p = row[i];
    wb[(size_t)j*H + i] = (short)f2bf(p * dw[i]);
    acc += db[i] * p;
  }
  red[t] = acc; __syncthreads();
  for (int s = 128; s > 0; s >>= 1){
    if (t < s) red[t] += red[t+s];
    __syncthreads();
  }
  if (t == 0) bo[j] = pb[j] + red[0];
}

// ---------------- x -> bf16 ----------------
__global__ __launch_bounds__(256) void cvt_x(const float* __restrict__ x, short* __restrict__ xb){
  int i = blockIdx.x*256 + threadIdx.x;
  const float4* p = (const float4*)(x + (size_t)i*8);
  float4 a = p[0], b = p[1];
  bf16x8 o;
  o[0]=(short)f2bf(a.x); o[1]=(short)f2bf(a.y); o[2]=(short)f2bf(a.z); o[3]=(short)f2bf(a.w);
  o[4]=(short)f2bf(b.x); o[5]=(short)f2bf(b.y); o[6]=(short)f2bf(b.z); o[7]=(short)f2bf(b.w);
  *(bf16x8*)(xb + (size_t)i*8) = o;
}

// ---------------- 128x128x(K=1024) bf16 GEMM, out = A @ W.T + bias -------------
// FINAL=false: z in {0,1,2} = k,q,v. q written [M][H] bf16; k,v written transposed
//              [B][H][L] bf16 (for column-softmax + context GEMM).
// FINAL=true:  single proj, fp32 output [M][H].
template<bool FINAL>
__global__ __launch_bounds__(256) void gemm_k(const short* __restrict__ A,
    const short* __restrict__ WBall, const float* __restrict__ Ball,
    void* o0, void* o1, void* o2){
  const int p  = FINAL ? 0 : blockIdx.z;
  const short* wb  = WBall + (size_t)p*H*H;
  const float* bia = Ball + p*H;
  const int n0 = blockIdx.x * 128;
  const int m0 = blockIdx.y * 128;

  __shared__ __align__(16) short lA[128*64];
  __shared__ __align__(16) short lB[128*64];

  const int tid  = threadIdx.x;
  const int lane = tid & 63;
  const int w    = tid >> 6;          // wave 0..3
  const int wr   = w >> 1, wc = w & 1;

  f32x4 acc[4][4] = {};

  const int sl = lane & 7, rl = lane >> 3;
  const int lsw = ((sl ^ rl) << 3);   // pre-swizzled source slot (elements)

  for (int kt = 0; kt < 16; ++kt){
    __syncthreads();
    const int kb = kt*64;
    #pragma unroll
    for (int c = 0; c < 4; ++c){
      const int r = (w*4+c)*8 + rl;
      g2l16(A  + (size_t)(m0 + r)*H + kb + lsw, &lA[(w*4+c)*512]);
      g2l16(wb + (size_t)(n0 + r)*H + kb + lsw, &lB[(w*4+c)*512]);
    }
    __syncthreads();
    const int q4 = lane >> 4, r16 = lane & 15;
    #pragma unroll
    for (int kk = 0; kk < 2; ++kk){
      const int slog = kk*4 + q4;
      bf16x8 af[4], bfv[4];
      #pragma unroll
      for (int mi = 0; mi < 4; ++mi){
        const int row = wr*64 + mi*16 + r16;
        af[mi] = *(const bf16x8*)&lA[row*64 + ((slog ^ (row & 7)) << 3)];
      }
      #pragma unroll
      for (int ni = 0; ni < 4; ++ni){
        const int row = wc*64 + ni*16 + r16;
        bfv[ni] = *(const bf16x8*)&lB[row*64 + ((slog ^ (row & 7)) << 3)];
      }
      #pragma unroll
      for (int mi = 0; mi < 4; ++mi)
        #pragma unroll
        for (int ni = 0; ni < 4; ++ni)
          acc[mi][ni] = mfma16(af[mi], bfv[ni], acc[mi][ni]);
    }
  }

  const int q4 = lane >> 4, r16 = lane & 15;
  if (FINAL){
    float* out = (float*)o0;
    #pragma unroll
    for (int ni=0;ni<4;++ni){
      const int n = n0 + wc*64 + ni*16 + r16;
      const float bv = bia[n];
      #pragma unroll
      for (int mi=0;mi<4;++mi){
        const int mb = m0 + wr*64 + mi*16 + q4*4;
        #pragma unroll
        for (int j=0;j<4;++j)
          out[(size_t)(mb+j)*H + n] = acc[mi][ni][j] + bv;
      }
    }
  } else if (p == 1){                       // queries, [M][H] bf16
    short* oq = (short*)o0;
    #pragma unroll
    for (int ni=0;ni<4;++ni){
      const int n = n0 + wc*64 + ni*16 + r16;
      const float bv = bia[n];
      #pragma unroll
      for (int mi=0;mi<4;++mi){
        const int mb = m0 + wr*64 + mi*16 + q4*4;
        #pragma unroll
        for (int j=0;j<4;++j)
          oq[(size_t)(mb+j)*H + n] = (short)f2bf(acc[mi][ni][j] + bv);
      }
    }
  } else {                                  // keys/values, transposed [B][H][L] bf16
    short* ot = (short*)((p==0) ? o1 : o2);
    #pragma unroll
    for (int ni=0;ni<4;++ni){
      const int n = n0 + wc*64 + ni*16 + r16;
      const float bv = bia[n];
      #pragma unroll
      for (int mi=0;mi<4;++mi){
        const int m = m0 + wr*64 + mi*16 + q4*4;
        const int bb = m >> 12, lpos = m & 4095;
        s16x4 v;
        #pragma unroll
        for (int j=0;j<4;++j) v[j] = (short)f2bf(acc[mi][ni][j] + bv);
        *(s16x4*)&ot[((size_t)bb*H + n)*LSEQ + lpos] = v;
      }
    }
  }
}

// ---------------- per-channel masked max / 1/denom over L ----------------------
__global__ __launch_bounds__(256) void key_stats(const short* __restrict__ kT,
    const int* __restrict__ mask, float* __restrict__ mx, float* __restrict__ rd){
  const int w = threadIdx.x >> 6, lane = threadIdx.x & 63;
  const int ch = blockIdx.x*4 + w;          // 0..4095  (b*1024 + channel)
  const int b = ch >> 10;
  const short* row = kT + (size_t)ch * LSEQ;
  const int* mrow = mask + (size_t)b * LSEQ;
  float vals[64];
  float m = -3e38f;
  #pragma unroll
  for (int it = 0; it < 8; ++it){
    const int l = it*512 + lane*8;
    bf16x8 v = *(const bf16x8*)&row[l];
    int4 k0 = *(const int4*)&mrow[l];
    int4 k1 = *(const int4*)&mrow[l+4];
    int mk[8] = {k0.x,k0.y,k0.z,k0.w,k1.x,k1.y,k1.z,k1.w};
    #pragma unroll
    for (int e=0;e<8;++e){
      float lg = mk[e] ? bf2f((unsigned short)v[e]) : -1e30f;
      vals[it*8+e] = lg;
      m = fmaxf(m, lg);
    }
  }
  #pragma unroll
  for (int off=32; off>=1; off>>=1) m = fmaxf(m, __shfl_xor(m, off));
  float s = 0.f;
  #pragma unroll
  for (int i=0;i<64;++i) s += __expf(vals[i]-m);
  #pragma unroll
  for (int off=32; off>=1; off>>=1) s += __shfl_xor(s, off);
  if (lane == 0){ mx[ch] = m; rd[ch] = 1.0f / s; }
}

// ---------------- context partial: [64c x 64d] += key_sm @ V^T over 1024 l -----
__global__ __launch_bounds__(256) void ctx_k(const short* __restrict__ kT,
    const short* __restrict__ vT, const int* __restrict__ mask,
    const float* __restrict__ mx, const float* __restrict__ rd,
    float* __restrict__ ctxP){
  const int lc = blockIdx.x, h = blockIdx.y, b = blockIdx.z;
  __shared__ __align__(16) short lK[64*64];
  __shared__ __align__(16) short lV[64*64];
  __shared__ float sMx[64], sRd[64];
  __shared__ int sMk[64];
  const int tid = threadIdx.x, lane = tid & 63, w = tid >> 6;
  if (tid < 64){
    const int ch = b*1024 + h*64 + tid;
    sMx[tid] = mx[ch]; sRd[tid] = rd[ch];
  }
  f32x4 acc[4] = {};
  const short* kb = kT + (size_t)(b*16 + h)*64*LSEQ;
  const short* vb = vT + (size_t)(b*16 + h)*64*LSEQ;
  const int l0 = lc*1024;
  const int sl = lane & 7, rl = lane >> 3;
  const int lsw = ((sl ^ rl) << 3);
  for (int kc = 0; kc < 16; ++kc){
    __syncthreads();
    const int lb = l0 + kc*64;
    #pragma unroll
    for (int c = 0; c < 2; ++c){
      const int r = (w*2+c)*8 + rl;
      g2l16(kb + (size_t)r*LSEQ + lb + lsw, &lK[(w*2+c)*512]);
      g2l16(vb + (size_t)r*LSEQ + lb + lsw, &lV[(w*2+c)*512]);
    }
    if (tid < 64) sMk[tid] = mask[(size_t)b*LSEQ + lb + tid];
    __syncthreads();
    { // in-place transform: k -> exp(masked(k)-max)/denom, bf16
      const int row = lane;
      const float mxr = sMx[row], rdr = sRd[row];
      #pragma unroll
      for (int k2 = 0; k2 < 2; ++k2){
        const int slog = w*2 + k2;
        const int sp = slog ^ (row & 7);
        bf16x8 v = *(bf16x8*)&lK[row*64 + (sp<<3)];
        bf16x8 o;
        #pragma unroll
        for (int e=0;e<8;++e){
          const float f = bf2f((unsigned short)v[e]);
          const float lg = sMk[slog*8+e] ? f : -1e30f;
          o[e] = (short)f2bf(__expf(lg - mxr) * rdr);
        }
        *(bf16x8*)&lK[row*64 + (sp<<3)] = o;
      }
    }
    __syncthreads();
    const int q4 = lane >> 4, r16 = lane & 15;
    #pragma unroll
    for (int kk = 0; kk < 2; ++kk){
      const int slog = kk*4 + q4;
      const int rowA = w*16 + r16;
      bf16x8 a = *(bf16x8*)&lK[rowA*64 + ((slog ^ (rowA & 7))<<3)];
      #pragma unroll
      for (int ni = 0; ni < 4; ++ni){
        const int rowB = ni*16 + r16;
        bf16x8 bv = *(bf16x8*)&lV[rowB*64 + ((slog ^ (rowB & 7))<<3)];
        acc[ni] = mfma16(a, bv, acc[ni]);
      }
    }
  }
  const int q4 = lane >> 4, r16 = lane & 15;
  float* op = ctxP + (((size_t)(b*16 + h)*4 + lc) << 12);
  #pragma unroll
  for (int ni=0;ni<4;++ni){
    const int d = ni*16 + r16;
    #pragma unroll
    for (int j=0;j<4;++j){
      const int c = w*16 + q4*4 + j;
      op[c*64 + d] = acc[ni][j];
    }
  }
}

// ---------------- query softmax (over 64 in-head ch) + attended -> agg bf16 ----
__global__ __launch_bounds__(256) void attd_k(const short* __restrict__ qb,
    const float* __restrict__ ctxP, const int* __restrict__ mask,
    short* __restrict__ agg){
  const int lcb = blockIdx.x, h = blockIdx.y, b = blockIdx.z;
  __shared__ __align__(16) short lQ[64*64];
  __shared__ __align__(16) short lCt[64*64];   // [d][c] swizzled, bf16
  const int tid = threadIdx.x, lane = tid & 63, w = tid >> 6;
  { // sum 4 context partials, transpose into lCt
    const int d = lane, g = w;
    const float* base = ctxP + ((size_t)(b*16 + h)*4 << 12);
    #pragma unroll
    for (int i=0;i<16;++i){
      const int c = g*16 + i;
      const float s = base[c*64+d] + base[4096+c*64+d] + base[8192+c*64+d] + base[12288+c*64+d];
      lCt[d*64 + ((((c>>3) ^ (d&7))<<3) | (c&7))] = (short)f2bf(s);
    }
  }
  const int l0g = b*LSEQ + lcb*1024;
  const int sl = lane & 7, rl = lane >> 3;
  const int lsw = ((sl ^ rl) << 3);
  for (int sc = 0; sc < 16; ++sc){
    __syncthreads();
    #pragma unroll
    for (int c = 0; c < 2; ++c){
      const int r = (w*2+c)*8 + rl;
      g2l16(qb + (size_t)(l0g + sc*64 + r)*H + h*64 + lsw, &lQ[(w*2+c)*512]);
    }
    __syncthreads();
    { // per-row softmax over the 64 head-channels (4 lanes cooperate per row)
      const int row = w*16 + (lane & 15);
      const int q4 = lane >> 4;
      const int mk = mask[(size_t)b*LSEQ + lcb*1024 + sc*64 + row];
      float vals[16];
      float mxv = -3e38f;
      #pragma unroll
      for (int k2=0;k2<2;++k2){
        const int slog = q4*2 + k2;
        const int sp = slog ^ (row & 7);
        bf16x8 v = *(bf16x8*)&lQ[row*64 + (sp<<3)];
        #pragma unroll
        for (int e=0;e<8;++e){
          const float f = bf2f((unsigned short)v[e]);
          vals[k2*8+e] = f;
          mxv = fmaxf(mxv, f);
        }
      }
      mxv = fmaxf(mxv, __shfl_xor(mxv, 16));
      mxv = fmaxf(mxv, __shfl_xor(mxv, 32));
      float s = 0.f;
      #pragma unroll
      for (int e=0;e<16;++e){ vals[e] = __expf(vals[e]-mxv); s += vals[e]; }
      s += __shfl_xor(s, 16);
      s += __shfl_xor(s, 32);
      const float inv = 1.0f / s;
      #pragma unroll
      for (int k2=0;k2<2;++k2){
        const int slog = q4*2 + k2;
        const int sp = slog ^ (row & 7);
        bf16x8 o;
        #pragma unroll
        for (int e=0;e<8;++e)
          o[e] = (short)f2bf(mk ? vals[k2*8+e]*inv : 0.015625f);  // masked -> exactly 1/64
        *(bf16x8*)&lQ[row*64 + (sp<<3)] = o;
      }
    }
    __syncthreads();
    f32x4 acc[4] = {};
    const int q4 = lane >> 4, r16 = lane & 15;
    #pragma unroll
    for (int kk=0;kk<2;++kk){
      const int slog = kk*4 + q4;
      const int rowA = w*16 + r16;
      bf16x8 a = *(bf16x8*)&lQ[rowA*64 + ((slog ^ (rowA&7))<<3)];
      #pragma unroll
      for (int ni=0;ni<4;++ni){
        const int rowB = ni*16 + r16;
        bf16x8 bv = *(bf16x8*)&lCt[rowB*64 + ((slog ^ (rowB&7))<<3)];
        acc[ni] = mfma16(a, bv, acc[ni]);
      }
    }
    #pragma unroll
    for (int ni=0;ni<4;++ni){
      const int d = ni*16 + r16;
      #pragma unroll
      for (int j=0;j<4;++j){
        const int lrow = w*16 + q4*4 + j;
        agg[(size_t)(l0g + sc*64 + lrow)*H + h*64 + d] = (short)f2bf(acc[ni][j]);
      }
    }
  }
}

extern "C" void kernel_launch(void* const* d_in, const int* in_sizes, int n_in,
                              void* d_out, int out_size, void* d_ws, size_t ws_size,
                              hipStream_t stream){
  (void)in_sizes; (void)n_in; (void)out_size; (void)ws_size;
  const float* x    = (const float*)d_in[0];
  const int*   mask = (const int*)d_in[1];
  const float* dw[4]; const float* db[4]; const float* pw[4]; const float* pb[4];
  for (int p2 = 0; p2 < 4; ++p2){        // 0=k,1=q,2=v,3=r
    dw[p2] = (const float*)d_in[2 + 4*p2];
    db[p2] = (const float*)d_in[3 + 4*p2];
    pw[p2] = (const float*)d_in[4 + 4*p2];
    pb[p2] = (const float*)d_in[5 + 4*p2];
  }
  char* ws = (char*)d_ws;
  short* WB   = (short*)(ws);                          // 8 MiB: 4 x [H][H] bf16
  float* BIAS = (float*)(ws + ((size_t)8<<20));        // 16 KiB
  float* MX   = BIAS + 4096;
  float* RD   = MX + 4096;
  short* XB   = (short*)(ws + ((size_t)9<<20));        // 32 MiB bf16 x
  short* QB   = (short*)(ws + ((size_t)41<<20));       // 32 MiB queries [M][H]
  short* KT   = (short*)(ws + ((size_t)73<<20));       // 32 MiB keys^T [B][H][L]
  short* VT   = (short*)(ws + ((size_t)105<<20));      // 32 MiB values^T
  float* CTXP = (float*)(ws + ((size_t)137<<20));      // 4 MiB context partials
  short* AGG  = XB;                                    // reuse (x dead after proj GEMM)

  for (int p2 = 0; p2 < 4; ++p2)
    prep_w<<<1024, 256, 0, stream>>>(pw[p2], dw[p2], db[p2], pb[p2],
                                     WB + (size_t)p2*H*H, BIAS + p2*H);
  cvt_x<<<8192, 256, 0, stream>>>(x, XB);
  gemm_k<false><<<dim3(8,128,3), 256, 0, stream>>>(XB, WB, BIAS, QB, KT, VT);
  key_stats<<<1024, 256, 0, stream>>>(KT, mask, MX, RD);
  ctx_k<<<dim3(4,16,4), 256, 0, stream>>>(KT, VT, mask, MX, RD, CTXP);
  attd_k<<<dim3(4,16,4), 256, 0, stream>>>(QB, CTXP, mask, AGG);
  gemm_k<true><<<dim3(8,128,1), 256, 0, stream>>>(AGG, WB + (size_t)3*H*H, BIAS + 3*H,
                                                  d_out, nullptr, nullptr);
}

// Round 2
// 239.612 us; speedup vs baseline: 1.2421x; 1.2421x over previous
//
#include <hip/hip_runtime.h>
#include <stdint.h>

#define H 1024
#define LSEQ 4096
#define NBATCH 4
#define MT (NBATCH*LSEQ)   // 16384 rows total

typedef __attribute__((ext_vector_type(8))) short bf16x8;
typedef __attribute__((ext_vector_type(4))) short s16x4;
typedef __attribute__((ext_vector_type(4))) float f32x4;

static __device__ __forceinline__ unsigned short f2bf(float f){
  union { float f; unsigned u; } v; v.f = f;
  unsigned u = v.u;
  return (unsigned short)((u + 0x7FFFu + ((u >> 16) & 1u)) >> 16);  // RNE
}
static __device__ __forceinline__ float bf2f(unsigned short h){
  union { unsigned u; float f; } v; v.u = ((unsigned)h) << 16;
  return v.f;
}
static __device__ __forceinline__ void g2l16(const void* g, void* l){
  __builtin_amdgcn_global_load_lds((const __attribute__((address_space(1))) void*)g,
                                   (__attribute__((address_space(3))) void*)l, 16, 0, 0);
}
static __device__ __forceinline__ f32x4 mfma16(bf16x8 a, bf16x8 b, f32x4 c){
  return __builtin_amdgcn_mfma_f32_16x16x32_bf16(a, b, c, 0, 0, 0);
}

// ---------------- weight prep: Wb = bf16(pw*dw), bias' = pb + db@pw.T ----------
struct P4 { const float* pw[4]; const float* dw[4]; const float* db[4]; const float* pb[4]; };

__global__ __launch_bounds__(256) void prep_w(P4 a, short* __restrict__ wb, float* __restrict__ bo){
  __shared__ float red[256];
  const int g = blockIdx.x, p = g >> 10, j = g & 1023, t = threadIdx.x;
  const float* row = a.pw[p] + (size_t)j * H;
  const float* dwp = a.dw[p];
  const float* dbp = a.db[p];
  float acc = 0.f;
  #pragma unroll
  for (int k = 0; k < 4; ++k){
    int i = k*256 + t;
    float pv = row[i];
    wb[((size_t)p*H + j)*H + i] = (short)f2bf(pv * dwp[i]);
    acc += dbp[i] * pv;
  }
  red[t] = acc; __syncthreads();
  for (int s = 128; s > 0; s >>= 1){
    if (t < s) red[t] += red[t+s];
    __syncthreads();
  }
  if (t == 0) bo[p*H + j] = a.pb[p][j] + red[0];
}

// ---------------- x -> bf16 ----------------
__global__ __launch_bounds__(256) void cvt_x(const float* __restrict__ x, short* __restrict__ xb){
  int i = blockIdx.x*256 + threadIdx.x;
  const float4* p = (const float4*)(x + (size_t)i*8);
  float4 a = p[0], b = p[1];
  bf16x8 o;
  o[0]=(short)f2bf(a.x); o[1]=(short)f2bf(a.y); o[2]=(short)f2bf(a.z); o[3]=(short)f2bf(a.w);
  o[4]=(short)f2bf(b.x); o[5]=(short)f2bf(b.y); o[6]=(short)f2bf(b.z); o[7]=(short)f2bf(b.w);
  *(bf16x8*)(xb + (size_t)i*8) = o;
}

// ============== 256x256 tile, BK=64, 8-wave, 4-phase counted-vmcnt GEMM ========
// out = A[M][1024] @ W[N][1024]^T + bias
// MODE 0: N=3072 fused k|q|v. n0>>10 routes: 0->KT transposed, 1->QB bf16, 2->VT.
// MODE 1: N=1024, fp32 out [M][H].
template<int MODE, int NBLK>
__global__ __launch_bounds__(512, 2) void gemm8(const short* __restrict__ A,
    const short* __restrict__ WBp, const float* __restrict__ bia,
    short* __restrict__ oq, short* __restrict__ okT, short* __restrict__ ovT,
    float* __restrict__ ofin){
  __shared__ __align__(16) short lA[2][256*64];
  __shared__ __align__(16) short lB[2][256*64];

  const int nwg = NBLK * 64;
  const int cpx = nwg >> 3;
  const int bid = blockIdx.x;
  const int swz = (bid & 7) * cpx + (bid >> 3);   // XCD-contiguous chunks
  const int mb = swz / NBLK, nb = swz % NBLK;     // n fastest within XCD -> A-panel L2 reuse
  const int m0 = mb * 256, n0 = nb * 256;

  const int tid  = threadIdx.x;
  const int lane = tid & 63;
  const int w    = tid >> 6;            // 0..7
  const int wm   = w >> 2, wn = w & 3;  // 2 x 4 wave grid; per-wave out 128x64
  const int q4 = lane >> 4, r16 = lane & 15;
  const int rl = lane >> 3, sl = lane & 7;
  const int srcsw = ((sl ^ rl) << 3);   // pre-swizzled global source slot (elements)

#define STAGE_A(BUF_, Q_, KB_) \
  g2l16(A + (size_t)(m0 + (Q_)*64 + w*8 + rl)*H + (KB_) + srcsw, \
        &lA[BUF_][((Q_)*64 + w*8)*64])
#define STAGE_B(BUF_, Q_, KB_) \
  g2l16(WBp + (size_t)(n0 + (Q_)*64 + w*8 + rl)*H + (KB_) + srcsw, \
        &lB[BUF_][((Q_)*64 + w*8)*64])
#define RD_A(dst, BUF_, MI8, KK) { const int row_ = wm*128 + (MI8)*16 + r16; \
  dst = *(const bf16x8*)&lA[BUF_][row_*64 + ((((KK)*4+q4) ^ (row_&7))<<3)]; }
#define RD_B(dst, BUF_, NI4, KK) { const int row_ = wn*64 + (NI4)*16 + r16; \
  dst = *(const bf16x8*)&lB[BUF_][row_*64 + ((((KK)*4+q4) ^ (row_&7))<<3)]; }

  f32x4 acc[8][4] = {};
  bf16x8 aF[4][2], bFa[2][2], bFb[2][2];

  // prologue: stage tile 0 (B quarters first, then A in first-needed order)
  STAGE_B(0,0,0); STAGE_B(0,1,0); STAGE_B(0,2,0); STAGE_B(0,3,0);
  STAGE_A(0,0,0); STAGE_A(0,2,0); STAGE_A(0,1,0); STAGE_A(0,3,0);
  asm volatile("s_waitcnt vmcnt(2)" ::: "memory");
  __builtin_amdgcn_s_barrier();
  __builtin_amdgcn_sched_barrier(0);

  #pragma unroll 2
  for (int t = 0; t < 16; ++t){
    const int buf = t & 1, sbuf = buf ^ 1;
    const int skb = ((t < 15) ? (t + 1) : 15) << 6;

    // ---- phase A: quadrant (mih0, nih0) ----
    #pragma unroll
    for (int mi = 0; mi < 4; ++mi){ RD_A(aF[mi][0], buf, mi, 0); RD_A(aF[mi][1], buf, mi, 1); }
    #pragma unroll
    for (int ni = 0; ni < 2; ++ni){ RD_B(bFa[ni][0], buf, ni, 0); RD_B(bFa[ni][1], buf, ni, 1); }
    STAGE_B(sbuf, 0, skb); STAGE_B(sbuf, 1, skb);
    __builtin_amdgcn_s_barrier();
    asm volatile("s_waitcnt lgkmcnt(0)" ::: "memory");
    __builtin_amdgcn_sched_barrier(0);
    __builtin_amdgcn_s_setprio(1);
    #pragma unroll
    for (int kk = 0; kk < 2; ++kk)
      #pragma unroll
      for (int mi = 0; mi < 4; ++mi)
        #pragma unroll
        for (int ni = 0; ni < 2; ++ni)
          acc[mi][ni] = mfma16(aF[mi][kk], bFa[ni][kk], acc[mi][ni]);
    __builtin_amdgcn_s_setprio(0);
    __builtin_amdgcn_s_barrier();
    __builtin_amdgcn_sched_barrier(0);

    // ---- phase B: quadrant (mih0, nih1) ----
    #pragma unroll
    for (int ni = 0; ni < 2; ++ni){ RD_B(bFb[ni][0], buf, 2+ni, 0); RD_B(bFb[ni][1], buf, 2+ni, 1); }
    STAGE_B(sbuf, 2, skb); STAGE_B(sbuf, 3, skb);
    __builtin_amdgcn_s_barrier();
    asm volatile("s_waitcnt lgkmcnt(0)" ::: "memory");
    __builtin_amdgcn_sched_barrier(0);
    __builtin_amdgcn_s_setprio(1);
    #pragma unroll
    for (int kk = 0; kk < 2; ++kk)
      #pragma unroll
      for (int mi = 0; mi < 4; ++mi)
        #pragma unroll
        for (int ni = 0; ni < 2; ++ni)
          acc[mi][2+ni] = mfma16(aF[mi][kk], bFb[ni][kk], acc[mi][2+ni]);
    __builtin_amdgcn_s_setprio(0);
    asm volatile("s_waitcnt vmcnt(4)" ::: "memory");   // current tile's Aq1/Aq3 landed
    __builtin_amdgcn_s_barrier();
    __builtin_amdgcn_sched_barrier(0);

    // ---- phase C: quadrant (mih1, nih0) ----
    #pragma unroll
    for (int mi = 0; mi < 4; ++mi){ RD_A(aF[mi][0], buf, 4+mi, 0); RD_A(aF[mi][1], buf, 4+mi, 1); }
    STAGE_A(sbuf, 0, skb); STAGE_A(sbuf, 2, skb);
    __builtin_amdgcn_s_barrier();
    asm volatile("s_waitcnt lgkmcnt(0)" ::: "memory");
    __builtin_amdgcn_sched_barrier(0);
    __builtin_amdgcn_s_setprio(1);
    #pragma unroll
    for (int kk = 0; kk < 2; ++kk)
      #pragma unroll
      for (int mi = 0; mi < 4; ++mi)
        #pragma unroll
        for (int ni = 0; ni < 2; ++ni)
          acc[4+mi][ni] = mfma16(aF[mi][kk], bFa[ni][kk], acc[4+mi][ni]);
    __builtin_amdgcn_s_setprio(0);
    __builtin_amdgcn_s_barrier();
    __builtin_amdgcn_sched_barrier(0);

    // ---- phase D: quadrant (mih1, nih1) ----
    STAGE_A(sbuf, 1, skb); STAGE_A(sbuf, 3, skb);
    __builtin_amdgcn_s_barrier();
    asm volatile("s_waitcnt lgkmcnt(0)" ::: "memory");
    __builtin_amdgcn_sched_barrier(0);
    __builtin_amdgcn_s_setprio(1);
    #pragma unroll
    for (int kk = 0; kk < 2; ++kk)
      #pragma unroll
      for (int mi = 0; mi < 4; ++mi)
        #pragma unroll
        for (int ni = 0; ni < 2; ++ni)
          acc[4+mi][2+ni] = mfma16(aF[mi][kk], bFb[ni][kk], acc[4+mi][2+ni]);
    __builtin_amdgcn_s_setprio(0);
    asm volatile("s_waitcnt vmcnt(2)" ::: "memory");   // next tile's B + Aq0/Aq2 landed
    __builtin_amdgcn_s_barrier();
    __builtin_amdgcn_sched_barrier(0);
  }
#undef STAGE_A
#undef STAGE_B
#undef RD_A
#undef RD_B

  // ---------------- epilogue ----------------
  if (MODE == 1){
    #pragma unroll
    for (int ni4 = 0; ni4 < 4; ++ni4){
      const int n = n0 + wn*64 + ni4*16 + r16;
      const float bv = bia[n];
      #pragma unroll
      for (int mi8 = 0; mi8 < 8; ++mi8){
        const int mbse = m0 + wm*128 + mi8*16 + q4*4;
        #pragma unroll
        for (int j = 0; j < 4; ++j)
          ofin[(size_t)(mbse+j)*H + n] = acc[mi8][ni4][j] + bv;
      }
    }
  } else {
    const int p = n0 >> 10;
    if (p == 1){                                  // queries -> [M][H] bf16
      #pragma unroll
      for (int ni4 = 0; ni4 < 4; ++ni4){
        const int n = n0 + wn*64 + ni4*16 + r16;
        const float bv = bia[n];
        const int ch = n & 1023;
        #pragma unroll
        for (int mi8 = 0; mi8 < 8; ++mi8){
          const int mbse = m0 + wm*128 + mi8*16 + q4*4;
          #pragma unroll
          for (int j = 0; j < 4; ++j)
            oq[(size_t)(mbse+j)*H + ch] = (short)f2bf(acc[mi8][ni4][j] + bv);
        }
      }
    } else {                                      // k/v -> transposed [B][H][L] bf16
      short* ot = (p == 0) ? okT : ovT;
      #pragma unroll
      for (int ni4 = 0; ni4 < 4; ++ni4){
        const int n = n0 + wn*64 + ni4*16 + r16;
        const float bv = bia[n];
        const int ch = n & 1023;
        #pragma unroll
        for (int mi8 = 0; mi8 < 8; ++mi8){
          const int m = m0 + wm*128 + mi8*16 + q4*4;
          const int bb = m >> 12, lpos = m & 4095;
          s16x4 v;
          #pragma unroll
          for (int j = 0; j < 4; ++j) v[j] = (short)f2bf(acc[mi8][ni4][j] + bv);
          *(s16x4*)&ot[((size_t)bb*H + ch)*LSEQ + lpos] = v;
        }
      }
    }
  }
}

// ---------------- per-channel masked max / 1/denom over L ----------------------
__global__ __launch_bounds__(256) void key_stats(const short* __restrict__ kT,
    const int* __restrict__ mask, float* __restrict__ mx, float* __restrict__ rd){
  const int w = threadIdx.x >> 6, lane = threadIdx.x & 63;
  const int ch = blockIdx.x*4 + w;          // 0..4095  (b*1024 + channel)
  const int b = ch >> 10;
  const short* row = kT + (size_t)ch * LSEQ;
  const int* mrow = mask + (size_t)b * LSEQ;
  float vals[64];
  float m = -3e38f;
  #pragma unroll
  for (int it = 0; it < 8; ++it){
    const int l = it*512 + lane*8;
    bf16x8 v = *(const bf16x8*)&row[l];
    int4 k0 = *(const int4*)&mrow[l];
    int4 k1 = *(const int4*)&mrow[l+4];
    int mk[8] = {k0.x,k0.y,k0.z,k0.w,k1.x,k1.y,k1.z,k1.w};
    #pragma unroll
    for (int e=0;e<8;++e){
      float lg = mk[e] ? bf2f((unsigned short)v[e]) : -1e30f;
      vals[it*8+e] = lg;
      m = fmaxf(m, lg);
    }
  }
  #pragma unroll
  for (int off=32; off>=1; off>>=1) m = fmaxf(m, __shfl_xor(m, off));
  float s = 0.f;
  #pragma unroll
  for (int i=0;i<64;++i) s += __expf(vals[i]-m);
  #pragma unroll
  for (int off=32; off>=1; off>>=1) s += __shfl_xor(s, off);
  if (lane == 0){ mx[ch] = m; rd[ch] = 1.0f / s; }
}

// ---------------- context partial: [64c x 64d] += key_sm @ V^T over 1024 l -----
__global__ __launch_bounds__(256) void ctx_k(const short* __restrict__ kT,
    const short* __restrict__ vT, const int* __restrict__ mask,
    const float* __restrict__ mx, const float* __restrict__ rd,
    float* __restrict__ ctxP){
  const int lc = blockIdx.x, h = blockIdx.y, b = blockIdx.z;
  __shared__ __align__(16) short lK[64*64];
  __shared__ __align__(16) short lV[64*64];
  __shared__ float sMx[64], sRd[64];
  __shared__ int sMk[64];
  const int tid = threadIdx.x, lane = tid & 63, w = tid >> 6;
  if (tid < 64){
    const int ch = b*1024 + h*64 + tid;
    sMx[tid] = mx[ch]; sRd[tid] = rd[ch];
  }
  f32x4 acc[4] = {};
  const short* kb = kT + (size_t)(b*16 + h)*64*LSEQ;
  const short* vb = vT + (size_t)(b*16 + h)*64*LSEQ;
  const int l0 = lc*1024;
  const int sl = lane & 7, rl = lane >> 3;
  const int lsw = ((sl ^ rl) << 3);
  for (int kc = 0; kc < 16; ++kc){
    __syncthreads();
    const int lb = l0 + kc*64;
    #pragma unroll
    for (int c = 0; c < 2; ++c){
      const int r = (w*2+c)*8 + rl;
      g2l16(kb + (size_t)r*LSEQ + lb + lsw, &lK[(w*2+c)*512]);
      g2l16(vb + (size_t)r*LSEQ + lb + lsw, &lV[(w*2+c)*512]);
    }
    if (tid < 64) sMk[tid] = mask[(size_t)b*LSEQ + lb + tid];
    __syncthreads();
    { // in-place transform: k -> exp(masked(k)-max)/denom, bf16
      const int row = lane;
      const float mxr = sMx[row], rdr = sRd[row];
      #pragma unroll
      for (int k2 = 0; k2 < 2; ++k2){
        const int slog = w*2 + k2;
        const int sp = slog ^ (row & 7);
        bf16x8 v = *(bf16x8*)&lK[row*64 + (sp<<3)];
        bf16x8 o;
        #pragma unroll
        for (int e=0;e<8;++e){
          const float f = bf2f((unsigned short)v[e]);
          const float lg = sMk[slog*8+e] ? f : -1e30f;
          o[e] = (short)f2bf(__expf(lg - mxr) * rdr);
        }
        *(bf16x8*)&lK[row*64 + (sp<<3)] = o;
      }
    }
    __syncthreads();
    const int q4 = lane >> 4, r16 = lane & 15;
    #pragma unroll
    for (int kk = 0; kk < 2; ++kk){
      const int slog = kk*4 + q4;
      const int rowA = w*16 + r16;
      bf16x8 a = *(bf16x8*)&lK[rowA*64 + ((slog ^ (rowA & 7))<<3)];
      #pragma unroll
      for (int ni = 0; ni < 4; ++ni){
        const int rowB = ni*16 + r16;
        bf16x8 bv = *(bf16x8*)&lV[rowB*64 + ((slog ^ (rowB & 7))<<3)];
        acc[ni] = mfma16(a, bv, acc[ni]);
      }
    }
  }
  const int q4 = lane >> 4, r16 = lane & 15;
  float* op = ctxP + (((size_t)(b*16 + h)*4 + lc) << 12);
  #pragma unroll
  for (int ni=0;ni<4;++ni){
    const int d = ni*16 + r16;
    #pragma unroll
    for (int j=0;j<4;++j){
      const int c = w*16 + q4*4 + j;
      op[c*64 + d] = acc[ni][j];
    }
  }
}

// ---------------- query softmax (over 64 in-head ch) + attended -> agg bf16 ----
__global__ __launch_bounds__(256) void attd_k(const short* __restrict__ qb,
    const float* __restrict__ ctxP, const int* __restrict__ mask,
    short* __restrict__ agg){
  const int lcb = blockIdx.x, h = blockIdx.y, b = blockIdx.z;
  __shared__ __align__(16) short lQ[64*64];
  __shared__ __align__(16) short lCt[64*64];   // [d][c] swizzled, bf16
  const int tid = threadIdx.x, lane = tid & 63, w = tid >> 6;
  { // sum 4 context partials, transpose into lCt
    const int d = lane, g = w;
    const float* base = ctxP + ((size_t)(b*16 + h)*4 << 12);
    #pragma unroll
    for (int i=0;i<16;++i){
      const int c = g*16 + i;
      const float s = base[c*64+d] + base[4096+c*64+d] + base[8192+c*64+d] + base[12288+c*64+d];
      lCt[d*64 + ((((c>>3) ^ (d&7))<<3) | (c&7))] = (short)f2bf(s);
    }
  }
  const int l0g = b*LSEQ + lcb*1024;
  const int sl = lane & 7, rl = lane >> 3;
  const int lsw = ((sl ^ rl) << 3);
  for (int sc = 0; sc < 16; ++sc){
    __syncthreads();
    #pragma unroll
    for (int c = 0; c < 2; ++c){
      const int r = (w*2+c)*8 + rl;
      g2l16(qb + (size_t)(l0g + sc*64 + r)*H + h*64 + lsw, &lQ[(w*2+c)*512]);
    }
    __syncthreads();
    { // per-row softmax over the 64 head-channels (4 lanes cooperate per row)
      const int row = w*16 + (lane & 15);
      const int q4 = lane >> 4;
      const int mk = mask[(size_t)b*LSEQ + lcb*1024 + sc*64 + row];
      float vals[16];
      float mxv = -3e38f;
      #pragma unroll
      for (int k2=0;k2<2;++k2){
        const int slog = q4*2 + k2;
        const int sp = slog ^ (row & 7);
        bf16x8 v = *(bf16x8*)&lQ[row*64 + (sp<<3)];
        #pragma unroll
        for (int e=0;e<8;++e){
          const float f = bf2f((unsigned short)v[e]);
          vals[k2*8+e] = f;
          mxv = fmaxf(mxv, f);
        }
      }
      mxv = fmaxf(mxv, __shfl_xor(mxv, 16));
      mxv = fmaxf(mxv, __shfl_xor(mxv, 32));
      float s = 0.f;
      #pragma unroll
      for (int e=0;e<16;++e){ vals[e] = __expf(vals[e]-mxv); s += vals[e]; }
      s += __shfl_xor(s, 16);
      s += __shfl_xor(s, 32);
      const float inv = 1.0f / s;
      #pragma unroll
      for (int k2=0;k2<2;++k2){
        const int slog = q4*2 + k2;
        const int sp = slog ^ (row & 7);
        bf16x8 o;
        #pragma unroll
        for (int e=0;e<8;++e)
          o[e] = (short)f2bf(mk ? vals[k2*8+e]*inv : 0.015625f);  // masked -> exactly 1/64
        *(bf16x8*)&lQ[row*64 + (sp<<3)] = o;
      }
    }
    __syncthreads();
    f32x4 acc[4] = {};
    const int q4 = lane >> 4, r16 = lane & 15;
    #pragma unroll
    for (int kk=0;kk<2;++kk){
      const int slog = kk*4 + q4;
      const int rowA = w*16 + r16;
      bf16x8 a = *(bf16x8*)&lQ[rowA*64 + ((slog ^ (rowA&7))<<3)];
      #pragma unroll
      for (int ni=0;ni<4;++ni){
        const int rowB = ni*16 + r16;
        bf16x8 bv = *(bf16x8*)&lCt[rowB*64 + ((slog ^ (rowB&7))<<3)];
        acc[ni] = mfma16(a, bv, acc[ni]);
      }
    }
    #pragma unroll
    for (int ni=0;ni<4;++ni){
      const int d = ni*16 + r16;
      #pragma unroll
      for (int j=0;j<4;++j){
        const int lrow = w*16 + q4*4 + j;
        agg[(size_t)(l0g + sc*64 + lrow)*H + h*64 + d] = (short)f2bf(acc[ni][j]);
      }
    }
  }
}

extern "C" void kernel_launch(void* const* d_in, const int* in_sizes, int n_in,
                              void* d_out, int out_size, void* d_ws, size_t ws_size,
                              hipStream_t stream){
  (void)in_sizes; (void)n_in; (void)out_size; (void)ws_size;
  const float* x    = (const float*)d_in[0];
  const int*   mask = (const int*)d_in[1];
  P4 prm;
  for (int p2 = 0; p2 < 4; ++p2){        // 0=k,1=q,2=v,3=r
    prm.dw[p2] = (const float*)d_in[2 + 4*p2];
    prm.db[p2] = (const float*)d_in[3 + 4*p2];
    prm.pw[p2] = (const float*)d_in[4 + 4*p2];
    prm.pb[p2] = (const float*)d_in[5 + 4*p2];
  }
  char* ws = (char*)d_ws;
  short* WB   = (short*)(ws);                          // 8 MiB: 4 x [H][H] bf16
  float* BIAS = (float*)(ws + ((size_t)8<<20));        // 16 KiB
  float* MX   = BIAS + 4096;
  float* RD   = MX + 4096;
  short* XB   = (short*)(ws + ((size_t)9<<20));        // 32 MiB bf16 x
  short* QB   = (short*)(ws + ((size_t)41<<20));       // 32 MiB queries [M][H]
  short* KT   = (short*)(ws + ((size_t)73<<20));       // 32 MiB keys^T [B][H][L]
  short* VT   = (short*)(ws + ((size_t)105<<20));      // 32 MiB values^T
  float* CTXP = (float*)(ws + ((size_t)137<<20));      // 4 MiB context partials
  short* AGG  = XB;                                    // reuse (x dead after proj GEMM)

  prep_w<<<4096, 256, 0, stream>>>(prm, WB, BIAS);
  cvt_x<<<8192, 256, 0, stream>>>(x, XB);
  gemm8<0,12><<<768, 512, 0, stream>>>(XB, WB, BIAS, QB, KT, VT, nullptr);
  key_stats<<<1024, 256, 0, stream>>>(KT, mask, MX, RD);
  ctx_k<<<dim3(4,16,4), 256, 0, stream>>>(KT, VT, mask, MX, RD, CTXP);
  attd_k<<<dim3(4,16,4), 256, 0, stream>>>(QB, CTXP, mask, AGG);
  gemm8<1,4><<<256, 512, 0, stream>>>(AGG, WB + (size_t)3*H*H, BIAS + 3*1024,
                                      nullptr, nullptr, nullptr, (float*)d_out);
}

// Round 3
// 227.776 us; speedup vs baseline: 1.3066x; 1.0520x over previous
//
#include <hip/hip_runtime.h>
#include <stdint.h>

#define H 1024
#define LSEQ 4096
#define NBATCH 4
#define MT (NBATCH*LSEQ)   // 16384 rows total

typedef __attribute__((ext_vector_type(8))) short bf16x8;
typedef __attribute__((ext_vector_type(4))) short s16x4;
typedef __attribute__((ext_vector_type(4))) float f32x4;

static __device__ __forceinline__ unsigned short f2bf(float f){
  union { float f; unsigned u; } v; v.f = f;
  unsigned u = v.u;
  return (unsigned short)((u + 0x7FFFu + ((u >> 16) & 1u)) >> 16);  // RNE
}
static __device__ __forceinline__ float bf2f(unsigned short h){
  union { unsigned u; float f; } v; v.u = ((unsigned)h) << 16;
  return v.f;
}
static __device__ __forceinline__ void g2l16(const void* g, void* l){
  __builtin_amdgcn_global_load_lds((const __attribute__((address_space(1))) void*)g,
                                   (__attribute__((address_space(3))) void*)l, 16, 0, 0);
}
static __device__ __forceinline__ f32x4 mfma16(bf16x8 a, bf16x8 b, f32x4 c){
  return __builtin_amdgcn_mfma_f32_16x16x32_bf16(a, b, c, 0, 0, 0);
}

// ---------------- weight prep: Wb = bf16(pw*dw), bias' = pb + db@pw.T ----------
struct P4 { const float* pw[4]; const float* dw[4]; const float* db[4]; const float* pb[4]; };

__global__ __launch_bounds__(256) void prep_w(P4 a, short* __restrict__ wb, float* __restrict__ bo){
  __shared__ float red[256];
  const int g = blockIdx.x, p = g >> 10, j = g & 1023, t = threadIdx.x;
  const float* row = a.pw[p] + (size_t)j * H;
  const float* dwp = a.dw[p];
  const float* dbp = a.db[p];
  float acc = 0.f;
  #pragma unroll
  for (int k = 0; k < 4; ++k){
    int i = k*256 + t;
    float pv = row[i];
    wb[((size_t)p*H + j)*H + i] = (short)f2bf(pv * dwp[i]);
    acc += dbp[i] * pv;
  }
  red[t] = acc; __syncthreads();
  for (int s = 128; s > 0; s >>= 1){
    if (t < s) red[t] += red[t+s];
    __syncthreads();
  }
  if (t == 0) bo[p*H + j] = a.pb[p][j] + red[0];
}

// ---------------- x -> bf16 ----------------
__global__ __launch_bounds__(256) void cvt_x(const float* __restrict__ x, short* __restrict__ xb){
  int i = blockIdx.x*256 + threadIdx.x;
  const float4* p = (const float4*)(x + (size_t)i*8);
  float4 a = p[0], b = p[1];
  bf16x8 o;
  o[0]=(short)f2bf(a.x); o[1]=(short)f2bf(a.y); o[2]=(short)f2bf(a.z); o[3]=(short)f2bf(a.w);
  o[4]=(short)f2bf(b.x); o[5]=(short)f2bf(b.y); o[6]=(short)f2bf(b.z); o[7]=(short)f2bf(b.w);
  *(bf16x8*)(xb + (size_t)i*8) = o;
}

// ============== 256x256 tile, BK=64, 8-wave, 2-phase counted-vmcnt GEMM ========
// out = A[M][1024] @ W[N][1024]^T + bias
// MODE 0: N=3072 fused k|q|v. n0>>10 routes: 0->KT transposed, 1->QB bf16, 2->VT.
// MODE 1: N=1024, fp32 out [M][H].
template<int MODE, int NBLK>
__global__ __launch_bounds__(512, 2) void gemm8(const short* __restrict__ A,
    const short* __restrict__ WBp, const float* __restrict__ bia,
    short* __restrict__ oq, short* __restrict__ okT, short* __restrict__ ovT,
    float* __restrict__ ofin){
  // lsm[0] = A tiles (double-buffered), lsm[1] = B tiles. Reused as C-staging in epilogue.
  __shared__ __align__(16) short lsm[2][2][256*64];

  const int nwg = NBLK * 64;
  const int cpx = nwg >> 3;
  const int bid = blockIdx.x;
  const int swz = (bid & 7) * cpx + (bid >> 3);   // XCD-contiguous chunks
  const int mb = swz / NBLK, nb = swz % NBLK;     // n fastest within XCD -> A-panel L2 reuse
  const int m0 = mb * 256, n0 = nb * 256;

  const int tid  = threadIdx.x;
  const int lane = tid & 63;
  const int w    = tid >> 6;            // 0..7
  const int wm   = w >> 2, wn = w & 3;  // 2 x 4 wave grid; per-wave out 128x64
  const int q4 = lane >> 4, r16 = lane & 15;
  const int rl = lane >> 3, sl = lane & 7;
  const int srcsw = ((sl ^ rl) << 3);   // pre-swizzled global source slot (elements)

#define STAGE_A(BUF_, Q_, KB_) \
  g2l16(A + (size_t)(m0 + (Q_)*64 + w*8 + rl)*H + (KB_) + srcsw, \
        &lsm[0][BUF_][((Q_)*64 + w*8)*64])
#define STAGE_B(BUF_, Q_, KB_) \
  g2l16(WBp + (size_t)(n0 + (Q_)*64 + w*8 + rl)*H + (KB_) + srcsw, \
        &lsm[1][BUF_][((Q_)*64 + w*8)*64])
#define RD_A(dst, BUF_, MI8, KK) { const int row_ = wm*128 + (MI8)*16 + r16; \
  dst = *(const bf16x8*)&lsm[0][BUF_][row_*64 + ((((KK)*4+q4) ^ (row_&7))<<3)]; }
#define RD_B(dst, BUF_, NI4, KK) { const int row_ = wn*64 + (NI4)*16 + r16; \
  dst = *(const bf16x8*)&lsm[1][BUF_][row_*64 + ((((KK)*4+q4) ^ (row_&7))<<3)]; }

  f32x4 acc[8][4] = {};
  bf16x8 aF[4][2], bFa[2][2], bFb[2][2];

  // prologue: stage tile 0 (B quarters first, then A in first-needed order)
  STAGE_B(0,0,0); STAGE_B(0,1,0); STAGE_B(0,2,0); STAGE_B(0,3,0);
  STAGE_A(0,0,0); STAGE_A(0,2,0); STAGE_A(0,1,0); STAGE_A(0,3,0);
  asm volatile("s_waitcnt vmcnt(2)" ::: "memory");
  __builtin_amdgcn_s_barrier();
  __builtin_amdgcn_sched_barrier(0);

  #pragma unroll 2
  for (int t = 0; t < 16; ++t){
    const int buf = t & 1, sbuf = buf ^ 1;
    const int skb = ((t < 15) ? (t + 1) : 15) << 6;

    // ---- phase AB: full N, first M-half (A quarters 0/2) ----
    #pragma unroll
    for (int mi = 0; mi < 4; ++mi){ RD_A(aF[mi][0], buf, mi, 0); RD_A(aF[mi][1], buf, mi, 1); }
    #pragma unroll
    for (int ni = 0; ni < 2; ++ni){ RD_B(bFa[ni][0], buf, ni, 0); RD_B(bFa[ni][1], buf, ni, 1); }
    #pragma unroll
    for (int ni = 0; ni < 2; ++ni){ RD_B(bFb[ni][0], buf, 2+ni, 0); RD_B(bFb[ni][1], buf, 2+ni, 1); }
    STAGE_B(sbuf, 0, skb); STAGE_B(sbuf, 1, skb);
    STAGE_B(sbuf, 2, skb); STAGE_B(sbuf, 3, skb);
    __builtin_amdgcn_s_barrier();
    asm volatile("s_waitcnt lgkmcnt(0)" ::: "memory");
    __builtin_amdgcn_sched_barrier(0);
    __builtin_amdgcn_s_setprio(1);
    #pragma unroll
    for (int kk = 0; kk < 2; ++kk)
      #pragma unroll
      for (int mi = 0; mi < 4; ++mi){
        #pragma unroll
        for (int ni = 0; ni < 2; ++ni)
          acc[mi][ni] = mfma16(aF[mi][kk], bFa[ni][kk], acc[mi][ni]);
        #pragma unroll
        for (int ni = 0; ni < 2; ++ni)
          acc[mi][2+ni] = mfma16(aF[mi][kk], bFb[ni][kk], acc[mi][2+ni]);
      }
    __builtin_amdgcn_s_setprio(0);
    asm volatile("s_waitcnt vmcnt(4)" ::: "memory");   // A q1/q3 of tile t landed
    __builtin_amdgcn_s_barrier();
    __builtin_amdgcn_sched_barrier(0);

    // ---- phase CD: full N, second M-half (A quarters 1/3) ----
    #pragma unroll
    for (int mi = 0; mi < 4; ++mi){ RD_A(aF[mi][0], buf, 4+mi, 0); RD_A(aF[mi][1], buf, 4+mi, 1); }
    STAGE_A(sbuf, 0, skb); STAGE_A(sbuf, 2, skb);
    STAGE_A(sbuf, 1, skb); STAGE_A(sbuf, 3, skb);
    __builtin_amdgcn_s_barrier();
    asm volatile("s_waitcnt lgkmcnt(0)" ::: "memory");
    __builtin_amdgcn_sched_barrier(0);
    __builtin_amdgcn_s_setprio(1);
    #pragma unroll
    for (int kk = 0; kk < 2; ++kk)
      #pragma unroll
      for (int mi = 0; mi < 4; ++mi){
        #pragma unroll
        for (int ni = 0; ni < 2; ++ni)
          acc[4+mi][ni] = mfma16(aF[mi][kk], bFa[ni][kk], acc[4+mi][ni]);
        #pragma unroll
        for (int ni = 0; ni < 2; ++ni)
          acc[4+mi][2+ni] = mfma16(aF[mi][kk], bFb[ni][kk], acc[4+mi][2+ni]);
      }
    __builtin_amdgcn_s_setprio(0);
    asm volatile("s_waitcnt vmcnt(2)" ::: "memory");   // next tile's B + A q0/q2 landed
    __builtin_amdgcn_s_barrier();
    __builtin_amdgcn_sched_barrier(0);
  }
#undef STAGE_A
#undef STAGE_B
#undef RD_A
#undef RD_B

  // ---------------- epilogue ----------------
  if (MODE == 1){
    #pragma unroll
    for (int ni4 = 0; ni4 < 4; ++ni4){
      const int n = n0 + wn*64 + ni4*16 + r16;
      const float bv = bia[n];
      #pragma unroll
      for (int mi8 = 0; mi8 < 8; ++mi8){
        const int mbse = m0 + wm*128 + mi8*16 + q4*4;
        #pragma unroll
        for (int j = 0; j < 4; ++j)
          ofin[(size_t)(mbse+j)*H + n] = acc[mi8][ni4][j] + bv;
      }
    }
  } else {
    const int p = n0 >> 10;
    if (p == 1){                                  // queries -> [M][H] bf16 (direct)
      #pragma unroll
      for (int ni4 = 0; ni4 < 4; ++ni4){
        const int n = n0 + wn*64 + ni4*16 + r16;
        const float bv = bia[n];
        const int ch = n & 1023;
        #pragma unroll
        for (int mi8 = 0; mi8 < 8; ++mi8){
          const int mbse = m0 + wm*128 + mi8*16 + q4*4;
          #pragma unroll
          for (int j = 0; j < 4; ++j)
            oq[(size_t)(mbse+j)*H + ch] = (short)f2bf(acc[mi8][ni4][j] + bv);
        }
      }
    } else {                                      // k/v -> transposed [B][H][L] via LDS stage
      // drain in-flight global_load_lds (tail stages target lsm) before reuse
      asm volatile("s_waitcnt vmcnt(0)" ::: "memory");
      __syncthreads();
      char* sC = (char*)&lsm[0][0][0];            // 128 KiB = 256 x 256 bf16, 512B rows
      #pragma unroll
      for (int ni4 = 0; ni4 < 4; ++ni4){
        const int cr = wn*64 + ni4*16 + r16;      // tile row = channel
        const float bv = bia[n0 + cr];
        #pragma unroll
        for (int mi8 = 0; mi8 < 8; ++mi8){
          const int s8 = wm*32 + mi8*4 + q4;      // 8B slot along m
          s16x4 v;
          #pragma unroll
          for (int j = 0; j < 4; ++j) v[j] = (short)f2bf(acc[mi8][ni4][j] + bv);
          *(s16x4*)(sC + cr*512 + ((s8 ^ ((cr & 7) << 1)) << 3)) = v;
        }
      }
      __syncthreads();
      short* ot = (p == 0) ? okT : ovT;
      const int ch0 = n0 & 1023, bb = m0 >> 12, lp0 = m0 & 4095;
      const int c = lane & 31;
      #pragma unroll
      for (int it = 0; it < 16; ++it){
        const int cr = it*16 + w*2 + (lane >> 5);
        bf16x8 vv = *(bf16x8*)(sC + cr*512 + ((c ^ (cr & 7)) << 4));
        *(bf16x8*)&ot[((size_t)bb*H + ch0 + cr)*LSEQ + lp0 + c*8] = vv;
      }
    }
  }
}

// ---------------- per-channel masked max / 1/denom over L ----------------------
__global__ __launch_bounds__(256) void key_stats(const short* __restrict__ kT,
    const int* __restrict__ mask, float* __restrict__ mx, float* __restrict__ rd){
  const int w = threadIdx.x >> 6, lane = threadIdx.x & 63;
  const int ch = blockIdx.x*4 + w;          // 0..4095  (b*1024 + channel)
  const int b = ch >> 10;
  const short* row = kT + (size_t)ch * LSEQ;
  const int* mrow = mask + (size_t)b * LSEQ;
  float vals[64];
  float m = -3e38f;
  #pragma unroll
  for (int it = 0; it < 8; ++it){
    const int l = it*512 + lane*8;
    bf16x8 v = *(const bf16x8*)&row[l];
    int4 k0 = *(const int4*)&mrow[l];
    int4 k1 = *(const int4*)&mrow[l+4];
    int mk[8] = {k0.x,k0.y,k0.z,k0.w,k1.x,k1.y,k1.z,k1.w};
    #pragma unroll
    for (int e=0;e<8;++e){
      float lg = mk[e] ? bf2f((unsigned short)v[e]) : -1e30f;
      vals[it*8+e] = lg;
      m = fmaxf(m, lg);
    }
  }
  #pragma unroll
  for (int off=32; off>=1; off>>=1) m = fmaxf(m, __shfl_xor(m, off));
  float s = 0.f;
  #pragma unroll
  for (int i=0;i<64;++i) s += __expf(vals[i]-m);
  #pragma unroll
  for (int off=32; off>=1; off>>=1) s += __shfl_xor(s, off);
  if (lane == 0){ mx[ch] = m; rd[ch] = 1.0f / s; }
}

// ---------------- context partial: [64c x 64d] += key_sm @ V^T over 1024 l -----
__global__ __launch_bounds__(256) void ctx_k(const short* __restrict__ kT,
    const short* __restrict__ vT, const int* __restrict__ mask,
    const float* __restrict__ mx, const float* __restrict__ rd,
    float* __restrict__ ctxP){
  const int lc = blockIdx.x, h = blockIdx.y, b = blockIdx.z;
  __shared__ __align__(16) short lK[64*64];
  __shared__ __align__(16) short lV[64*64];
  __shared__ float sMx[64], sRd[64];
  __shared__ int sMk[64];
  const int tid = threadIdx.x, lane = tid & 63, w = tid >> 6;
  if (tid < 64){
    const int ch = b*1024 + h*64 + tid;
    sMx[tid] = mx[ch]; sRd[tid] = rd[ch];
  }
  f32x4 acc[4] = {};
  const short* kb = kT + (size_t)(b*16 + h)*64*LSEQ;
  const short* vb = vT + (size_t)(b*16 + h)*64*LSEQ;
  const int l0 = lc*1024;
  const int sl = lane & 7, rl = lane >> 3;
  const int lsw = ((sl ^ rl) << 3);
  for (int kc = 0; kc < 16; ++kc){
    __syncthreads();
    const int lb = l0 + kc*64;
    #pragma unroll
    for (int c = 0; c < 2; ++c){
      const int r = (w*2+c)*8 + rl;
      g2l16(kb + (size_t)r*LSEQ + lb + lsw, &lK[(w*2+c)*512]);
      g2l16(vb + (size_t)r*LSEQ + lb + lsw, &lV[(w*2+c)*512]);
    }
    if (tid < 64) sMk[tid] = mask[(size_t)b*LSEQ + lb + tid];
    __syncthreads();
    { // in-place transform: k -> exp(masked(k)-max)/denom, bf16
      const int row = lane;
      const float mxr = sMx[row], rdr = sRd[row];
      #pragma unroll
      for (int k2 = 0; k2 < 2; ++k2){
        const int slog = w*2 + k2;
        const int sp = slog ^ (row & 7);
        bf16x8 v = *(bf16x8*)&lK[row*64 + (sp<<3)];
        bf16x8 o;
        #pragma unroll
        for (int e=0;e<8;++e){
          const float f = bf2f((unsigned short)v[e]);
          const float lg = sMk[slog*8+e] ? f : -1e30f;
          o[e] = (short)f2bf(__expf(lg - mxr) * rdr);
        }
        *(bf16x8*)&lK[row*64 + (sp<<3)] = o;
      }
    }
    __syncthreads();
    const int q4 = lane >> 4, r16 = lane & 15;
    #pragma unroll
    for (int kk = 0; kk < 2; ++kk){
      const int slog = kk*4 + q4;
      const int rowA = w*16 + r16;
      bf16x8 a = *(bf16x8*)&lK[rowA*64 + ((slog ^ (rowA & 7))<<3)];
      #pragma unroll
      for (int ni = 0; ni < 4; ++ni){
        const int rowB = ni*16 + r16;
        bf16x8 bv = *(bf16x8*)&lV[rowB*64 + ((slog ^ (rowB & 7))<<3)];
        acc[ni] = mfma16(a, bv, acc[ni]);
      }
    }
  }
  const int q4 = lane >> 4, r16 = lane & 15;
  float* op = ctxP + (((size_t)(b*16 + h)*4 + lc) << 12);
  #pragma unroll
  for (int ni=0;ni<4;++ni){
    const int d = ni*16 + r16;
    #pragma unroll
    for (int j=0;j<4;++j){
      const int c = w*16 + q4*4 + j;
      op[c*64 + d] = acc[ni][j];
    }
  }
}

// ---------------- query softmax (over 64 in-head ch) + attended -> agg bf16 ----
__global__ __launch_bounds__(256) void attd_k(const short* __restrict__ qb,
    const float* __restrict__ ctxP, const int* __restrict__ mask,
    short* __restrict__ agg){
  const int lcb = blockIdx.x, h = blockIdx.y, b = blockIdx.z;
  __shared__ __align__(16) short lQ[64*64];
  __shared__ __align__(16) short lCt[64*64];   // [d][c] swizzled, bf16
  const int tid = threadIdx.x, lane = tid & 63, w = tid >> 6;
  { // sum 4 context partials, transpose into lCt
    const int d = lane, g = w;
    const float* base = ctxP + ((size_t)(b*16 + h)*4 << 12);
    #pragma unroll
    for (int i=0;i<16;++i){
      const int c = g*16 + i;
      const float s = base[c*64+d] + base[4096+c*64+d] + base[8192+c*64+d] + base[12288+c*64+d];
      lCt[d*64 + ((((c>>3) ^ (d&7))<<3) | (c&7))] = (short)f2bf(s);
    }
  }
  const int l0g = b*LSEQ + lcb*1024;
  const int sl = lane & 7, rl = lane >> 3;
  const int lsw = ((sl ^ rl) << 3);
  for (int sc = 0; sc < 16; ++sc){
    __syncthreads();
    #pragma unroll
    for (int c = 0; c < 2; ++c){
      const int r = (w*2+c)*8 + rl;
      g2l16(qb + (size_t)(l0g + sc*64 + r)*H + h*64 + lsw, &lQ[(w*2+c)*512]);
    }
    __syncthreads();
    { // per-row softmax over the 64 head-channels (4 lanes cooperate per row)
      const int row = w*16 + (lane & 15);
      const int q4 = lane >> 4;
      const int mk = mask[(size_t)b*LSEQ + lcb*1024 + sc*64 + row];
      float vals[16];
      float mxv = -3e38f;
      #pragma unroll
      for (int k2=0;k2<2;++k2){
        const int slog = q4*2 + k2;
        const int sp = slog ^ (row & 7);
        bf16x8 v = *(bf16x8*)&lQ[row*64 + (sp<<3)];
        #pragma unroll
        for (int e=0;e<8;++e){
          const float f = bf2f((unsigned short)v[e]);
          vals[k2*8+e] = f;
          mxv = fmaxf(mxv, f);
        }
      }
      mxv = fmaxf(mxv, __shfl_xor(mxv, 16));
      mxv = fmaxf(mxv, __shfl_xor(mxv, 32));
      float s = 0.f;
      #pragma unroll
      for (int e=0;e<16;++e){ vals[e] = __expf(vals[e]-mxv); s += vals[e]; }
      s += __shfl_xor(s, 16);
      s += __shfl_xor(s, 32);
      const float inv = 1.0f / s;
      #pragma unroll
      for (int k2=0;k2<2;++k2){
        const int slog = q4*2 + k2;
        const int sp = slog ^ (row & 7);
        bf16x8 o;
        #pragma unroll
        for (int e=0;e<8;++e)
          o[e] = (short)f2bf(mk ? vals[k2*8+e]*inv : 0.015625f);  // masked -> exactly 1/64
        *(bf16x8*)&lQ[row*64 + (sp<<3)] = o;
      }
    }
    __syncthreads();
    f32x4 acc[4] = {};
    const int q4 = lane >> 4, r16 = lane & 15;
    #pragma unroll
    for (int kk=0;kk<2;++kk){
      const int slog = kk*4 + q4;
      const int rowA = w*16 + r16;
      bf16x8 a = *(bf16x8*)&lQ[rowA*64 + ((slog ^ (rowA&7))<<3)];
      #pragma unroll
      for (int ni=0;ni<4;++ni){
        const int rowB = ni*16 + r16;
        bf16x8 bv = *(bf16x8*)&lCt[rowB*64 + ((slog ^ (rowB&7))<<3)];
        acc[ni] = mfma16(a, bv, acc[ni]);
      }
    }
    #pragma unroll
    for (int ni=0;ni<4;++ni){
      const int d = ni*16 + r16;
      #pragma unroll
      for (int j=0;j<4;++j){
        const int lrow = w*16 + q4*4 + j;
        agg[(size_t)(l0g + sc*64 + lrow)*H + h*64 + d] = (short)f2bf(acc[ni][j]);
      }
    }
  }
}

extern "C" void kernel_launch(void* const* d_in, const int* in_sizes, int n_in,
                              void* d_out, int out_size, void* d_ws, size_t ws_size,
                              hipStream_t stream){
  (void)in_sizes; (void)n_in; (void)out_size; (void)ws_size;
  const float* x    = (const float*)d_in[0];
  const int*   mask = (const int*)d_in[1];
  P4 prm;
  for (int p2 = 0; p2 < 4; ++p2){        // 0=k,1=q,2=v,3=r
    prm.dw[p2] = (const float*)d_in[2 + 4*p2];
    prm.db[p2] = (const float*)d_in[3 + 4*p2];
    prm.pw[p2] = (const float*)d_in[4 + 4*p2];
    prm.pb[p2] = (const float*)d_in[5 + 4*p2];
  }
  char* ws = (char*)d_ws;
  short* WB   = (short*)(ws);                          // 8 MiB: 4 x [H][H] bf16
  float* BIAS = (float*)(ws + ((size_t)8<<20));        // 16 KiB
  float* MX   = BIAS + 4096;
  float* RD   = MX + 4096;
  short* XB   = (short*)(ws + ((size_t)9<<20));        // 32 MiB bf16 x
  short* QB   = (short*)(ws + ((size_t)41<<20));       // 32 MiB queries [M][H]
  short* KT   = (short*)(ws + ((size_t)73<<20));       // 32 MiB keys^T [B][H][L]
  short* VT   = (short*)(ws + ((size_t)105<<20));      // 32 MiB values^T
  float* CTXP = (float*)(ws + ((size_t)137<<20));      // 4 MiB context partials
  short* AGG  = XB;                                    // reuse (x dead after proj GEMM)

  prep_w<<<4096, 256, 0, stream>>>(prm, WB, BIAS);
  cvt_x<<<8192, 256, 0, stream>>>(x, XB);
  gemm8<0,12><<<768, 512, 0, stream>>>(XB, WB, BIAS, QB, KT, VT, nullptr);
  key_stats<<<1024, 256, 0, stream>>>(KT, mask, MX, RD);
  ctx_k<<<dim3(4,16,4), 256, 0, stream>>>(KT, VT, mask, MX, RD, CTXP);
  attd_k<<<dim3(4,16,4), 256, 0, stream>>>(QB, CTXP, mask, AGG);
  gemm8<1,4><<<256, 512, 0, stream>>>(AGG, WB + (size_t)3*H*H, BIAS + 3*1024,
                                      nullptr, nullptr, nullptr, (float*)d_out);
}

// Round 4
// 225.643 us; speedup vs baseline: 1.3190x; 1.0095x over previous
//
#include <hip/hip_runtime.h>
#include <stdint.h>

#define H 1024
#define LSEQ 4096
#define NBATCH 4
#define MT (NBATCH*LSEQ)   // 16384 rows total

typedef __attribute__((ext_vector_type(8))) short bf16x8;
typedef __attribute__((ext_vector_type(4))) short s16x4;
typedef __attribute__((ext_vector_type(4))) float f32x4;

static __device__ __forceinline__ unsigned short f2bf(float f){
  union { float f; unsigned u; } v; v.f = f;
  unsigned u = v.u;
  return (unsigned short)((u + 0x7FFFu + ((u >> 16) & 1u)) >> 16);  // RNE
}
static __device__ __forceinline__ float bf2f(unsigned short h){
  union { unsigned u; float f; } v; v.u = ((unsigned)h) << 16;
  return v.f;
}
static __device__ __forceinline__ void g2l16(const void* g, void* l){
  __builtin_amdgcn_global_load_lds((const __attribute__((address_space(1))) void*)g,
                                   (__attribute__((address_space(3))) void*)l, 16, 0, 0);
}
static __device__ __forceinline__ f32x4 mfma16(bf16x8 a, bf16x8 b, f32x4 c){
  return __builtin_amdgcn_mfma_f32_16x16x32_bf16(a, b, c, 0, 0, 0);
}

// ---------------- weight prep: Wb = bf16(pw*dw), bias' = pb + db@pw.T ----------
struct P4 { const float* pw[4]; const float* dw[4]; const float* db[4]; const float* pb[4]; };

__global__ __launch_bounds__(256) void prep_w(P4 a, short* __restrict__ wb, float* __restrict__ bo){
  __shared__ float red[256];
  const int g = blockIdx.x, p = g >> 10, j = g & 1023, t = threadIdx.x;
  const float* row = a.pw[p] + (size_t)j * H;
  const float* dwp = a.dw[p];
  const float* dbp = a.db[p];
  float acc = 0.f;
  #pragma unroll
  for (int k = 0; k < 4; ++k){
    int i = k*256 + t;
    float pv = row[i];
    wb[((size_t)p*H + j)*H + i] = (short)f2bf(pv * dwp[i]);
    acc += dbp[i] * pv;
  }
  red[t] = acc; __syncthreads();
  for (int s = 128; s > 0; s >>= 1){
    if (t < s) red[t] += red[t+s];
    __syncthreads();
  }
  if (t == 0) bo[p*H + j] = a.pb[p][j] + red[0];
}

// ---------------- x -> bf16 ----------------
__global__ __launch_bounds__(256) void cvt_x(const float* __restrict__ x, short* __restrict__ xb){
  int i = blockIdx.x*256 + threadIdx.x;
  const float4* p = (const float4*)(x + (size_t)i*8);
  float4 a = p[0], b = p[1];
  bf16x8 o;
  o[0]=(short)f2bf(a.x); o[1]=(short)f2bf(a.y); o[2]=(short)f2bf(a.z); o[3]=(short)f2bf(a.w);
  o[4]=(short)f2bf(b.x); o[5]=(short)f2bf(b.y); o[6]=(short)f2bf(b.z); o[7]=(short)f2bf(b.w);
  *(bf16x8*)(xb + (size_t)i*8) = o;
}

// ============== 256x256 tile, BK=64, 8-wave, 2-phase counted-vmcnt GEMM ========
// Free-running phases: only correctness syncs (counted vmcnt + barrier at phase
// ends); no pre-MFMA barrier / lgkm drain -> compiler interleaves ds_read with
// MFMA, waves drift and overlap LDS-pipe vs matrix-pipe across the SIMD.
// out = A[M][1024] @ W[N][1024]^T + bias
// MODE 0: N=3072 fused k|q|v. n0>>10 routes: 0->KT transposed, 1->QB bf16, 2->VT.
// MODE 1: N=1024, fp32 out [M][H].
template<int MODE, int NBLK>
__global__ __launch_bounds__(512, 2) void gemm8(const short* __restrict__ A,
    const short* __restrict__ WBp, const float* __restrict__ bia,
    short* __restrict__ oq, short* __restrict__ okT, short* __restrict__ ovT,
    float* __restrict__ ofin){
  // lsm[0] = A tiles (double-buffered), lsm[1] = B tiles. Reused as C-staging in epilogue.
  __shared__ __align__(16) short lsm[2][2][256*64];

  const int nwg = NBLK * 64;
  const int cpx = nwg >> 3;
  const int bid = blockIdx.x;
  const int swz = (bid & 7) * cpx + (bid >> 3);   // XCD-contiguous chunks
  const int mb = swz / NBLK, nb = swz % NBLK;     // n fastest within XCD -> A-panel L2 reuse
  const int m0 = mb * 256, n0 = nb * 256;

  const int tid  = threadIdx.x;
  const int lane = tid & 63;
  const int w    = tid >> 6;            // 0..7
  const int wm   = w >> 2, wn = w & 3;  // 2 x 4 wave grid; per-wave out 128x64
  const int q4 = lane >> 4, r16 = lane & 15;
  const int rl = lane >> 3, sl = lane & 7;
  const int srcsw = ((sl ^ rl) << 3);   // pre-swizzled global source slot (elements)

#define STAGE_A(BUF_, Q_, KB_) \
  g2l16(A + (size_t)(m0 + (Q_)*64 + w*8 + rl)*H + (KB_) + srcsw, \
        &lsm[0][BUF_][((Q_)*64 + w*8)*64])
#define STAGE_B(BUF_, Q_, KB_) \
  g2l16(WBp + (size_t)(n0 + (Q_)*64 + w*8 + rl)*H + (KB_) + srcsw, \
        &lsm[1][BUF_][((Q_)*64 + w*8)*64])
#define RD_A(dst, BUF_, MI8, KK) { const int row_ = wm*128 + (MI8)*16 + r16; \
  dst = *(const bf16x8*)&lsm[0][BUF_][row_*64 + ((((KK)*4+q4) ^ (row_&7))<<3)]; }
#define RD_B(dst, BUF_, NI4, KK) { const int row_ = wn*64 + (NI4)*16 + r16; \
  dst = *(const bf16x8*)&lsm[1][BUF_][row_*64 + ((((KK)*4+q4) ^ (row_&7))<<3)]; }

  f32x4 acc[8][4] = {};
  bf16x8 aF[4][2], bFa[2][2], bFb[2][2];

  // prologue: stage tile 0 (B quarters first, then A in first-needed order)
  STAGE_B(0,0,0); STAGE_B(0,1,0); STAGE_B(0,2,0); STAGE_B(0,3,0);
  STAGE_A(0,0,0); STAGE_A(0,2,0); STAGE_A(0,1,0); STAGE_A(0,3,0);
  asm volatile("s_waitcnt vmcnt(2)" ::: "memory");
  __builtin_amdgcn_s_barrier();

  #pragma unroll 2
  for (int t = 0; t < 16; ++t){
    const int buf = t & 1, sbuf = buf ^ 1;
    const int skb = ((t < 15) ? (t + 1) : 15) << 6;

    // ---- phase AB: full N, first M-half (A quarters 0/2) ----
    #pragma unroll
    for (int mi = 0; mi < 4; ++mi){ RD_A(aF[mi][0], buf, mi, 0); RD_A(aF[mi][1], buf, mi, 1); }
    #pragma unroll
    for (int ni = 0; ni < 2; ++ni){ RD_B(bFa[ni][0], buf, ni, 0); RD_B(bFa[ni][1], buf, ni, 1); }
    #pragma unroll
    for (int ni = 0; ni < 2; ++ni){ RD_B(bFb[ni][0], buf, 2+ni, 0); RD_B(bFb[ni][1], buf, 2+ni, 1); }
    STAGE_B(sbuf, 0, skb); STAGE_B(sbuf, 1, skb);
    STAGE_B(sbuf, 2, skb); STAGE_B(sbuf, 3, skb);
    __builtin_amdgcn_s_setprio(1);
    #pragma unroll
    for (int kk = 0; kk < 2; ++kk)
      #pragma unroll
      for (int mi = 0; mi < 4; ++mi){
        #pragma unroll
        for (int ni = 0; ni < 2; ++ni)
          acc[mi][ni] = mfma16(aF[mi][kk], bFa[ni][kk], acc[mi][ni]);
        #pragma unroll
        for (int ni = 0; ni < 2; ++ni)
          acc[mi][2+ni] = mfma16(aF[mi][kk], bFb[ni][kk], acc[mi][2+ni]);
      }
    __builtin_amdgcn_s_setprio(0);
    asm volatile("s_waitcnt vmcnt(4)" ::: "memory");   // A q1/q3 of tile t landed
    __builtin_amdgcn_s_barrier();

    // ---- phase CD: full N, second M-half (A quarters 1/3) ----
    #pragma unroll
    for (int mi = 0; mi < 4; ++mi){ RD_A(aF[mi][0], buf, 4+mi, 0); RD_A(aF[mi][1], buf, 4+mi, 1); }
    STAGE_A(sbuf, 0, skb); STAGE_A(sbuf, 2, skb);
    STAGE_A(sbuf, 1, skb); STAGE_A(sbuf, 3, skb);
    __builtin_amdgcn_s_setprio(1);
    #pragma unroll
    for (int kk = 0; kk < 2; ++kk)
      #pragma unroll
      for (int mi = 0; mi < 4; ++mi){
        #pragma unroll
        for (int ni = 0; ni < 2; ++ni)
          acc[4+mi][ni] = mfma16(aF[mi][kk], bFa[ni][kk], acc[4+mi][ni]);
        #pragma unroll
        for (int ni = 0; ni < 2; ++ni)
          acc[4+mi][2+ni] = mfma16(aF[mi][kk], bFb[ni][kk], acc[4+mi][2+ni]);
      }
    __builtin_amdgcn_s_setprio(0);
    asm volatile("s_waitcnt vmcnt(2)" ::: "memory");   // next tile's B + A q0/q2 landed
    __builtin_amdgcn_s_barrier();
  }
#undef STAGE_A
#undef STAGE_B
#undef RD_A
#undef RD_B

  // ---------------- epilogue ----------------
  if (MODE == 1){
    #pragma unroll
    for (int ni4 = 0; ni4 < 4; ++ni4){
      const int n = n0 + wn*64 + ni4*16 + r16;
      const float bv = bia[n];
      #pragma unroll
      for (int mi8 = 0; mi8 < 8; ++mi8){
        const int mbse = m0 + wm*128 + mi8*16 + q4*4;
        #pragma unroll
        for (int j = 0; j < 4; ++j)
          ofin[(size_t)(mbse+j)*H + n] = acc[mi8][ni4][j] + bv;
      }
    }
  } else {
    const int p = n0 >> 10;
    if (p == 1){                                  // queries -> [M][H] bf16 (direct)
      #pragma unroll
      for (int ni4 = 0; ni4 < 4; ++ni4){
        const int n = n0 + wn*64 + ni4*16 + r16;
        const float bv = bia[n];
        const int ch = n & 1023;
        #pragma unroll
        for (int mi8 = 0; mi8 < 8; ++mi8){
          const int mbse = m0 + wm*128 + mi8*16 + q4*4;
          #pragma unroll
          for (int j = 0; j < 4; ++j)
            oq[(size_t)(mbse+j)*H + ch] = (short)f2bf(acc[mi8][ni4][j] + bv);
        }
      }
    } else {                                      // k/v -> transposed [B][H][L] via LDS stage
      // drain in-flight global_load_lds (tail stages target lsm) before reuse
      asm volatile("s_waitcnt vmcnt(0)" ::: "memory");
      __syncthreads();
      char* sC = (char*)&lsm[0][0][0];            // 128 KiB = 256 x 256 bf16, 512B rows
      #pragma unroll
      for (int ni4 = 0; ni4 < 4; ++ni4){
        const int cr = wn*64 + ni4*16 + r16;      // tile row = channel
        const float bv = bia[n0 + cr];
        #pragma unroll
        for (int mi8 = 0; mi8 < 8; ++mi8){
          const int s8 = wm*32 + mi8*4 + q4;      // 8B slot along m
          s16x4 v;
          #pragma unroll
          for (int j = 0; j < 4; ++j) v[j] = (short)f2bf(acc[mi8][ni4][j] + bv);
          *(s16x4*)(sC + cr*512 + ((s8 ^ ((cr & 7) << 1)) << 3)) = v;
        }
      }
      __syncthreads();
      short* ot = (p == 0) ? okT : ovT;
      const int ch0 = n0 & 1023, bb = m0 >> 12, lp0 = m0 & 4095;
      const int c = lane & 31;
      #pragma unroll
      for (int it = 0; it < 16; ++it){
        const int cr = it*16 + w*2 + (lane >> 5);
        bf16x8 vv = *(bf16x8*)(sC + cr*512 + ((c ^ (cr & 7)) << 4));
        *(bf16x8*)&ot[((size_t)bb*H + ch0 + cr)*LSEQ + lp0 + c*8] = vv;
      }
    }
  }
}

// ---------------- per-channel masked max / 1/denom over L ----------------------
__global__ __launch_bounds__(256) void key_stats(const short* __restrict__ kT,
    const int* __restrict__ mask, float* __restrict__ mx, float* __restrict__ rd){
  const int w = threadIdx.x >> 6, lane = threadIdx.x & 63;
  const int ch = blockIdx.x*4 + w;          // 0..4095  (b*1024 + channel)
  const int b = ch >> 10;
  const short* row = kT + (size_t)ch * LSEQ;
  const int* mrow = mask + (size_t)b * LSEQ;
  float vals[64];
  float m = -3e38f;
  #pragma unroll
  for (int it = 0; it < 8; ++it){
    const int l = it*512 + lane*8;
    bf16x8 v = *(const bf16x8*)&row[l];
    int4 k0 = *(const int4*)&mrow[l];
    int4 k1 = *(const int4*)&mrow[l+4];
    int mk[8] = {k0.x,k0.y,k0.z,k0.w,k1.x,k1.y,k1.z,k1.w};
    #pragma unroll
    for (int e=0;e<8;++e){
      float lg = mk[e] ? bf2f((unsigned short)v[e]) : -1e30f;
      vals[it*8+e] = lg;
      m = fmaxf(m, lg);
    }
  }
  #pragma unroll
  for (int off=32; off>=1; off>>=1) m = fmaxf(m, __shfl_xor(m, off));
  float s = 0.f;
  #pragma unroll
  for (int i=0;i<64;++i) s += __expf(vals[i]-m);
  #pragma unroll
  for (int off=32; off>=1; off>>=1) s += __shfl_xor(s, off);
  if (lane == 0){ mx[ch] = m; rd[ch] = 1.0f / s; }
}

// ---------------- context partial: [64c x 64d] += key_sm @ V^T over 1024 l -----
__global__ __launch_bounds__(256) void ctx_k(const short* __restrict__ kT,
    const short* __restrict__ vT, const int* __restrict__ mask,
    const float* __restrict__ mx, const float* __restrict__ rd,
    float* __restrict__ ctxP){
  const int lc = blockIdx.x, h = blockIdx.y, b = blockIdx.z;
  __shared__ __align__(16) short lK[64*64];
  __shared__ __align__(16) short lV[64*64];
  __shared__ float sMx[64], sRd[64];
  __shared__ int sMk[64];
  const int tid = threadIdx.x, lane = tid & 63, w = tid >> 6;
  if (tid < 64){
    const int ch = b*1024 + h*64 + tid;
    sMx[tid] = mx[ch]; sRd[tid] = rd[ch];
  }
  f32x4 acc[4] = {};
  const short* kb = kT + (size_t)(b*16 + h)*64*LSEQ;
  const short* vb = vT + (size_t)(b*16 + h)*64*LSEQ;
  const int l0 = lc*1024;
  const int sl = lane & 7, rl = lane >> 3;
  const int lsw = ((sl ^ rl) << 3);
  for (int kc = 0; kc < 16; ++kc){
    __syncthreads();
    const int lb = l0 + kc*64;
    #pragma unroll
    for (int c = 0; c < 2; ++c){
      const int r = (w*2+c)*8 + rl;
      g2l16(kb + (size_t)r*LSEQ + lb + lsw, &lK[(w*2+c)*512]);
      g2l16(vb + (size_t)r*LSEQ + lb + lsw, &lV[(w*2+c)*512]);
    }
    if (tid < 64) sMk[tid] = mask[(size_t)b*LSEQ + lb + tid];
    __syncthreads();
    { // in-place transform: k -> exp(masked(k)-max)/denom, bf16
      const int row = lane;
      const float mxr = sMx[row], rdr = sRd[row];
      #pragma unroll
      for (int k2 = 0; k2 < 2; ++k2){
        const int slog = w*2 + k2;
        const int sp = slog ^ (row & 7);
        bf16x8 v = *(bf16x8*)&lK[row*64 + (sp<<3)];
        bf16x8 o;
        #pragma unroll
        for (int e=0;e<8;++e){
          const float f = bf2f((unsigned short)v[e]);
          const float lg = sMk[slog*8+e] ? f : -1e30f;
          o[e] = (short)f2bf(__expf(lg - mxr) * rdr);
        }
        *(bf16x8*)&lK[row*64 + (sp<<3)] = o;
      }
    }
    __syncthreads();
    const int q4 = lane >> 4, r16 = lane & 15;
    #pragma unroll
    for (int kk = 0; kk < 2; ++kk){
      const int slog = kk*4 + q4;
      const int rowA = w*16 + r16;
      bf16x8 a = *(bf16x8*)&lK[rowA*64 + ((slog ^ (rowA & 7))<<3)];
      #pragma unroll
      for (int ni = 0; ni < 4; ++ni){
        const int rowB = ni*16 + r16;
        bf16x8 bv = *(bf16x8*)&lV[rowB*64 + ((slog ^ (rowB & 7))<<3)];
        acc[ni] = mfma16(a, bv, acc[ni]);
      }
    }
  }
  const int q4 = lane >> 4, r16 = lane & 15;
  float* op = ctxP + (((size_t)(b*16 + h)*4 + lc) << 12);
  #pragma unroll
  for (int ni=0;ni<4;++ni){
    const int d = ni*16 + r16;
    #pragma unroll
    for (int j=0;j<4;++j){
      const int c = w*16 + q4*4 + j;
      op[c*64 + d] = acc[ni][j];
    }
  }
}

// ---------------- query softmax (over 64 in-head ch) + attended -> agg bf16 ----
__global__ __launch_bounds__(256) void attd_k(const short* __restrict__ qb,
    const float* __restrict__ ctxP, const int* __restrict__ mask,
    short* __restrict__ agg){
  const int lcb = blockIdx.x, h = blockIdx.y, b = blockIdx.z;
  __shared__ __align__(16) short lQ[64*64];
  __shared__ __align__(16) short lCt[64*64];   // [d][c] swizzled, bf16
  const int tid = threadIdx.x, lane = tid & 63, w = tid >> 6;
  { // sum 4 context partials, transpose into lCt
    const int d = lane, g = w;
    const float* base = ctxP + ((size_t)(b*16 + h)*4 << 12);
    #pragma unroll
    for (int i=0;i<16;++i){
      const int c = g*16 + i;
      const float s = base[c*64+d] + base[4096+c*64+d] + base[8192+c*64+d] + base[12288+c*64+d];
      lCt[d*64 + ((((c>>3) ^ (d&7))<<3) | (c&7))] = (short)f2bf(s);
    }
  }
  const int l0g = b*LSEQ + lcb*1024;
  const int sl = lane & 7, rl = lane >> 3;
  const int lsw = ((sl ^ rl) << 3);
  for (int sc = 0; sc < 16; ++sc){
    __syncthreads();
    #pragma unroll
    for (int c = 0; c < 2; ++c){
      const int r = (w*2+c)*8 + rl;
      g2l16(qb + (size_t)(l0g + sc*64 + r)*H + h*64 + lsw, &lQ[(w*2+c)*512]);
    }
    __syncthreads();
    { // per-row softmax over the 64 head-channels (4 lanes cooperate per row)
      const int row = w*16 + (lane & 15);
      const int q4 = lane >> 4;
      const int mk = mask[(size_t)b*LSEQ + lcb*1024 + sc*64 + row];
      float vals[16];
      float mxv = -3e38f;
      #pragma unroll
      for (int k2=0;k2<2;++k2){
        const int slog = q4*2 + k2;
        const int sp = slog ^ (row & 7);
        bf16x8 v = *(bf16x8*)&lQ[row*64 + (sp<<3)];
        #pragma unroll
        for (int e=0;e<8;++e){
          const float f = bf2f((unsigned short)v[e]);
          vals[k2*8+e] = f;
          mxv = fmaxf(mxv, f);
        }
      }
      mxv = fmaxf(mxv, __shfl_xor(mxv, 16));
      mxv = fmaxf(mxv, __shfl_xor(mxv, 32));
      float s = 0.f;
      #pragma unroll
      for (int e=0;e<16;++e){ vals[e] = __expf(vals[e]-mxv); s += vals[e]; }
      s += __shfl_xor(s, 16);
      s += __shfl_xor(s, 32);
      const float inv = 1.0f / s;
      #pragma unroll
      for (int k2=0;k2<2;++k2){
        const int slog = q4*2 + k2;
        const int sp = slog ^ (row & 7);
        bf16x8 o;
        #pragma unroll
        for (int e=0;e<8;++e)
          o[e] = (short)f2bf(mk ? vals[k2*8+e]*inv : 0.015625f);  // masked -> exactly 1/64
        *(bf16x8*)&lQ[row*64 + (sp<<3)] = o;
      }
    }
    __syncthreads();
    f32x4 acc[4] = {};
    const int q4 = lane >> 4, r16 = lane & 15;
    #pragma unroll
    for (int kk=0;kk<2;++kk){
      const int slog = kk*4 + q4;
      const int rowA = w*16 + r16;
      bf16x8 a = *(bf16x8*)&lQ[rowA*64 + ((slog ^ (rowA&7))<<3)];
      #pragma unroll
      for (int ni=0;ni<4;++ni){
        const int rowB = ni*16 + r16;
        bf16x8 bv = *(bf16x8*)&lCt[rowB*64 + ((slog ^ (rowB&7))<<3)];
        acc[ni] = mfma16(a, bv, acc[ni]);
      }
    }
    #pragma unroll
    for (int ni=0;ni<4;++ni){
      const int d = ni*16 + r16;
      #pragma unroll
      for (int j=0;j<4;++j){
        const int lrow = w*16 + q4*4 + j;
        agg[(size_t)(l0g + sc*64 + lrow)*H + h*64 + d] = (short)f2bf(acc[ni][j]);
      }
    }
  }
}

extern "C" void kernel_launch(void* const* d_in, const int* in_sizes, int n_in,
                              void* d_out, int out_size, void* d_ws, size_t ws_size,
                              hipStream_t stream){
  (void)in_sizes; (void)n_in; (void)out_size; (void)ws_size;
  const float* x    = (const float*)d_in[0];
  const int*   mask = (const int*)d_in[1];
  P4 prm;
  for (int p2 = 0; p2 < 4; ++p2){        // 0=k,1=q,2=v,3=r
    prm.dw[p2] = (const float*)d_in[2 + 4*p2];
    prm.db[p2] = (const float*)d_in[3 + 4*p2];
    prm.pw[p2] = (const float*)d_in[4 + 4*p2];
    prm.pb[p2] = (const float*)d_in[5 + 4*p2];
  }
  char* ws = (char*)d_ws;
  short* WB   = (short*)(ws);                          // 8 MiB: 4 x [H][H] bf16
  float* BIAS = (float*)(ws + ((size_t)8<<20));        // 16 KiB
  float* MX   = BIAS + 4096;
  float* RD   = MX + 4096;
  short* XB   = (short*)(ws + ((size_t)9<<20));        // 32 MiB bf16 x
  short* QB   = (short*)(ws + ((size_t)41<<20));       // 32 MiB queries [M][H]
  short* KT   = (short*)(ws + ((size_t)73<<20));       // 32 MiB keys^T [B][H][L]
  short* VT   = (short*)(ws + ((size_t)105<<20));      // 32 MiB values^T
  float* CTXP = (float*)(ws + ((size_t)137<<20));      // 4 MiB context partials
  short* AGG  = XB;                                    // reuse (x dead after proj GEMM)

  prep_w<<<4096, 256, 0, stream>>>(prm, WB, BIAS);
  cvt_x<<<8192, 256, 0, stream>>>(x, XB);
  gemm8<0,12><<<768, 512, 0, stream>>>(XB, WB, BIAS, QB, KT, VT, nullptr);
  key_stats<<<1024, 256, 0, stream>>>(KT, mask, MX, RD);
  ctx_k<<<dim3(4,16,4), 256, 0, stream>>>(KT, VT, mask, MX, RD, CTXP);
  attd_k<<<dim3(4,16,4), 256, 0, stream>>>(QB, CTXP, mask, AGG);
  gemm8<1,4><<<256, 512, 0, stream>>>(AGG, WB + (size_t)3*H*H, BIAS + 3*1024,
                                      nullptr, nullptr, nullptr, (float*)d_out);
}